// Round 1
// baseline (603.159 us; speedup 1.0000x reference)
//
#include <hip/hip_runtime.h>

#define EPS 1e-5f

typedef unsigned short u16;
typedef __attribute__((ext_vector_type(8))) u16 u16x8;
typedef __attribute__((ext_vector_type(4))) u16 u16x4;
typedef __attribute__((ext_vector_type(8))) __bf16 bf16x8;
typedef __attribute__((ext_vector_type(4))) float f32x4;

__device__ __forceinline__ u16 f2bf(float f) {
  unsigned u = __float_as_uint(f);
  u += 0x7fffu + ((u >> 16) & 1u);  // RNE
  return (u16)(u >> 16);
}
__device__ __forceinline__ float bf2f(u16 h) {
  return __uint_as_float(((unsigned)h) << 16);
}
__device__ __forceinline__ f32x4 mfma16(u16x8 a, u16x8 b, f32x4 c) {
  return __builtin_amdgcn_mfma_f32_16x16x32_bf16(
      __builtin_bit_cast(bf16x8, a), __builtin_bit_cast(bf16x8, b), c, 0, 0, 0);
}

// ---------------- K0: pos[h][n][d] = rel_h[h,d,hh] + rel_w[h,d,ww], n = ww*32+hh
__global__ void k_pos(const float* __restrict__ rel_h, const float* __restrict__ rel_w,
                      float* __restrict__ pos_t) {
  int t = blockIdx.x * 256 + threadIdx.x;   // 8*1024*64 = 524288 exact
  int d = t & 63;
  int n = (t >> 6) & 1023;
  int h = t >> 16;
  int hh = n & 31, ww = n >> 5;
  pos_t[t] = rel_h[(h * 64 + d) * 32 + hh] + rel_w[(h * 64 + d) * 32 + ww];
}

// ---------------- K1: s = W_start @ x + b ; store q hi/lo (n-major) + q hi (d-major)
// grid (8 o-tiles, 16 n-tiles, 32 b), 256 thr (4 waves), tile 64x64, BK=64, split-bf16 (3 MFMA)
__global__ __launch_bounds__(256) void k_conv(
    const float* __restrict__ x, const float* __restrict__ Ws, const float* __restrict__ bs,
    u16* __restrict__ qh, u16* __restrict__ ql, u16* __restrict__ qd) {
  __shared__ u16 wt_h[64 * 72], wt_l[64 * 72], xt_h[64 * 72], xt_l[64 * 72];
  __shared__ u16 cb[64 * 64];
  const int ob = blockIdx.x, on = blockIdx.y, b = blockIdx.z;
  const int o0 = ob * 64, n0 = on * 64;
  const int t = threadIdx.x;
  const int w = t >> 6, lane = t & 63, g = lane >> 4, li = lane & 15;

  f32x4 zz = {0.f, 0.f, 0.f, 0.f};
  f32x4 acc[4];
#pragma unroll
  for (int i = 0; i < 4; ++i) acc[i] = zz;

  for (int kc = 0; kc < 8; ++kc) {
    const int c0 = kc * 64;
    __syncthreads();
    {  // stage W tile [64 o][64 c] -> hi/lo, pitch 72
      int o = t & 63, cc = (t >> 6) * 16;
      const float* src = Ws + (size_t)(o0 + o) * 512 + c0 + cc;
      u16 hi[16], lo[16];
#pragma unroll
      for (int k = 0; k < 4; ++k) {
        f32x4 f = *(const f32x4*)(src + 4 * k);
#pragma unroll
        for (int j = 0; j < 4; ++j) {
          float v = f[j];
          hi[4 * k + j] = f2bf(v);
          lo[4 * k + j] = f2bf(v - bf2f(hi[4 * k + j]));
        }
      }
      u16x8 p0 = {hi[0], hi[1], hi[2], hi[3], hi[4], hi[5], hi[6], hi[7]};
      u16x8 p1 = {hi[8], hi[9], hi[10], hi[11], hi[12], hi[13], hi[14], hi[15]};
      u16x8 q0 = {lo[0], lo[1], lo[2], lo[3], lo[4], lo[5], lo[6], lo[7]};
      u16x8 q1 = {lo[8], lo[9], lo[10], lo[11], lo[12], lo[13], lo[14], lo[15]};
      *(u16x8*)&wt_h[o * 72 + cc] = p0;
      *(u16x8*)&wt_h[o * 72 + cc + 8] = p1;
      *(u16x8*)&wt_l[o * 72 + cc] = q0;
      *(u16x8*)&wt_l[o * 72 + cc + 8] = q1;
    }
    {  // stage x tile transposed -> xt[n][c], pitch 72 (banks spread via c over all lanes)
      int c = t & 63, nc = (t >> 6) * 16;
      const float* src = x + ((size_t)b * 512 + c0 + c) * 1024 + n0 + nc;
#pragma unroll
      for (int k = 0; k < 4; ++k) {
        f32x4 f = *(const f32x4*)(src + 4 * k);
#pragma unroll
        for (int j = 0; j < 4; ++j) {
          float v = f[j];
          u16 hv = f2bf(v);
          xt_h[(nc + 4 * k + j) * 72 + c] = hv;
          xt_l[(nc + 4 * k + j) * 72 + c] = f2bf(v - bf2f(hv));
        }
      }
    }
    __syncthreads();
    u16x8 ah[2], al[2];
#pragma unroll
    for (int ks = 0; ks < 2; ++ks) {
      ah[ks] = *(const u16x8*)&wt_h[(16 * w + li) * 72 + g * 8 + 32 * ks];
      al[ks] = *(const u16x8*)&wt_l[(16 * w + li) * 72 + g * 8 + 32 * ks];
    }
#pragma unroll
    for (int ks = 0; ks < 2; ++ks) {
#pragma unroll
      for (int nf = 0; nf < 4; ++nf) {
        u16x8 bh = *(const u16x8*)&xt_h[(16 * nf + li) * 72 + g * 8 + 32 * ks];
        u16x8 bl = *(const u16x8*)&xt_l[(16 * nf + li) * 72 + g * 8 + 32 * ks];
        acc[nf] = mfma16(ah[ks], bh, acc[nf]);
        acc[nf] = mfma16(ah[ks], bl, acc[nf]);
        acc[nf] = mfma16(al[ks], bh, acc[nf]);
      }
    }
  }
  const int bh = b * 8 + ob;  // o-tile == head (64-aligned)
  float bias[4];
#pragma unroll
  for (int r = 0; r < 4; ++r) bias[r] = bs[o0 + 16 * w + g * 4 + r];
#pragma unroll
  for (int nf = 0; nf < 4; ++nf) {
    int n = n0 + 16 * nf + li;
    u16 hv[4], lv[4];
#pragma unroll
    for (int r = 0; r < 4; ++r) {
      float v = acc[nf][r] + bias[r];
      hv[r] = f2bf(v);
      lv[r] = f2bf(v - bf2f(hv[r]));
      cb[(16 * w + g * 4 + r) * 64 + 16 * nf + li] = hv[r];
    }
    u16x4 ph = {hv[0], hv[1], hv[2], hv[3]};
    u16x4 pl = {lv[0], lv[1], lv[2], lv[3]};
    size_t base = ((size_t)bh * 1024 + n) * 64 + 16 * w + g * 4;
    *(u16x4*)(qh + base) = ph;
    *(u16x4*)(ql + base) = pl;
  }
  __syncthreads();
  {  // d-major hi copy via LDS bounce (coalesced 128B rows)
    int o = t >> 2, sg = t & 3;
    u16x8 v0 = *(const u16x8*)&cb[o * 64 + sg * 16];
    u16x8 v1 = *(const u16x8*)&cb[o * 64 + sg * 16 + 8];
    size_t base = ((size_t)bh * 64 + o) * 1024 + n0 + sg * 16;
    *(u16x8*)(qd + base) = v0;
    *(u16x8*)(qd + base + 8) = v1;
  }
}

// ---------------- K2: flash attention + online stats + fused linear (partial) per (b,h)
// 256 blocks (one per bh), 512 thr (8 waves). JBLK=128, KBLK=64.
__global__ __launch_bounds__(512) void k_attn(
    const u16* __restrict__ qh, const u16* __restrict__ ql, const u16* __restrict__ qd,
    const float* __restrict__ pos_t, const float* __restrict__ Wlin,
    float* __restrict__ pout, float* __restrict__ qsum_g, float* __restrict__ sump2_g) {
  __shared__ u16 at_h[128 * 72], at_l[128 * 72];  // queries (q/scale+pos) hi/lo
  __shared__ u16 kt_h[64 * 72], kt_l[64 * 72];    // key tile hi/lo
  __shared__ u16 pt[128 * 72];                    // P (bf16), per-wave 16-row strips
  __shared__ u16 ol_h[128 * 72], ol_l[128 * 72];  // O/l split for linear MFMA
  __shared__ u16 wl_h[64 * 72], wl_l[64 * 72];    // W_lin split
  __shared__ float qs[64];
  __shared__ float wvar[8];

  const int bh = blockIdx.x, b = bh >> 3, h = bh & 7;
  const int t = threadIdx.x, w = t >> 6, lane = t & 63, g = lane >> 4, li = lane & 15;
  const u16* qhb = qh + (size_t)bh * 65536;
  const u16* qlb = ql + (size_t)bh * 65536;
  const u16* qdb = qd + (size_t)bh * 65536;
  const float* posb = pos_t + (size_t)h * 65536;
  const float SCALE_INV = 0.088388347648318447f;  // 1/sqrt(512/4)
  f32x4 zz = {0.f, 0.f, 0.f, 0.f};

  {  // stage W_lin hi/lo
    int e = t >> 3, ds = (t & 7) * 8;
    const float* src = Wlin + e * 64 + ds;
    f32x4 f0 = *(const f32x4*)src, f1 = *(const f32x4*)(src + 4);
    u16 hi[8], lo[8];
#pragma unroll
    for (int k = 0; k < 8; ++k) {
      float v = (k < 4) ? f0[k] : f1[k - 4];
      hi[k] = f2bf(v);
      lo[k] = f2bf(v - bf2f(hi[k]));
    }
    u16x8 p = {hi[0], hi[1], hi[2], hi[3], hi[4], hi[5], hi[6], hi[7]};
    u16x8 q = {lo[0], lo[1], lo[2], lo[3], lo[4], lo[5], lo[6], lo[7]};
    *(u16x8*)&wl_h[e * 72 + ds] = p;
    *(u16x8*)&wl_l[e * 72 + ds] = q;
  }
  if (t < 8) wvar[t] = 0.f;
  {  // qsum[d] = sum_n q[d,n]  (deterministic tree)
    float* qpart = (float*)ol_h;  // alias (ol not yet used)
    float acc = 0.f;
    for (int i = 0; i < 128; ++i) {
      int n = w + 8 * i;
      acc += bf2f(qhb[n * 64 + lane]) + bf2f(qlb[n * 64 + lane]);
    }
    qpart[w * 64 + lane] = acc;
    __syncthreads();
    if (t < 64) {
      float s = 0.f;
#pragma unroll
      for (int ww2 = 0; ww2 < 8; ++ww2) s += qpart[ww2 * 64 + t];
      qs[t] = s;
    }
    __syncthreads();
  }

  for (int jt = 0; jt < 8; ++jt) {
    const int j0 = jt * 128;
    __syncthreads();
    {  // stage queries a' = (qh+ql)/scale + pos, split hi/lo
      int jl = t >> 2, ds = (t & 3) * 16;
      const u16* sh = qhb + (j0 + jl) * 64 + ds;
      const u16* sl = qlb + (j0 + jl) * 64 + ds;
      const float* sp = posb + (j0 + jl) * 64 + ds;
      u16x8 hh0 = *(const u16x8*)sh, hh1 = *(const u16x8*)(sh + 8);
      u16x8 ll0 = *(const u16x8*)sl, ll1 = *(const u16x8*)(sl + 8);
      u16 A[16], L[16];
#pragma unroll
      for (int k = 0; k < 16; ++k) {
        u16 hv = (k < 8) ? hh0[k] : hh1[k - 8];
        u16 lv = (k < 8) ? ll0[k] : ll1[k - 8];
        float v = (bf2f(hv) + bf2f(lv)) * SCALE_INV + sp[k];
        A[k] = f2bf(v);
        L[k] = f2bf(v - bf2f(A[k]));
      }
      u16x8 a0 = {A[0], A[1], A[2], A[3], A[4], A[5], A[6], A[7]};
      u16x8 a1 = {A[8], A[9], A[10], A[11], A[12], A[13], A[14], A[15]};
      u16x8 b0 = {L[0], L[1], L[2], L[3], L[4], L[5], L[6], L[7]};
      u16x8 b1 = {L[8], L[9], L[10], L[11], L[12], L[13], L[14], L[15]};
      *(u16x8*)&at_h[jl * 72 + ds] = a0;
      *(u16x8*)&at_h[jl * 72 + ds + 8] = a1;
      *(u16x8*)&at_l[jl * 72 + ds] = b0;
      *(u16x8*)&at_l[jl * 72 + ds + 8] = b1;
    }
    __syncthreads();
    u16x8 qa_h[2], qa_l[2];
#pragma unroll
    for (int ks = 0; ks < 2; ++ks) {
      qa_h[ks] = *(const u16x8*)&at_h[(16 * w + li) * 72 + g * 8 + 32 * ks];
      qa_l[ks] = *(const u16x8*)&at_l[(16 * w + li) * 72 + g * 8 + 32 * ks];
    }
    float m[4], lsum[4], s2[4];
    f32x4 O[4];
#pragma unroll
    for (int r = 0; r < 4; ++r) {
      m[r] = -3.0e38f;
      lsum[r] = 0.f;
      s2[r] = 0.f;
    }
#pragma unroll
    for (int df = 0; df < 4; ++df) O[df] = zz;

    for (int kc = 0; kc < 16; ++kc) {
      const int k0 = kc * 64;
      __syncthreads();
      {  // stage key tile
        int key = t >> 3, ds = (t & 7) * 8;
        *(u16x8*)&kt_h[key * 72 + ds] = *(const u16x8*)(qhb + (k0 + key) * 64 + ds);
        *(u16x8*)&kt_l[key * 72 + ds] = *(const u16x8*)(qlb + (k0 + key) * 64 + ds);
      }
      __syncthreads();
      f32x4 S[4] = {zz, zz, zz, zz};
#pragma unroll
      for (int ks = 0; ks < 2; ++ks) {
#pragma unroll
        for (int nf = 0; nf < 4; ++nf) {
          u16x8 kh = *(const u16x8*)&kt_h[(16 * nf + li) * 72 + g * 8 + 32 * ks];
          u16x8 kl = *(const u16x8*)&kt_l[(16 * nf + li) * 72 + g * 8 + 32 * ks];
          S[nf] = mfma16(qa_h[ks], kh, S[nf]);
          S[nf] = mfma16(qa_h[ks], kl, S[nf]);
          S[nf] = mfma16(qa_l[ks], kh, S[nf]);
        }
      }
      // online softmax (lane-partial l / sum(P^2); only row-max needs per-tile butterfly)
      float tm[4];
#pragma unroll
      for (int r = 0; r < 4; ++r)
        tm[r] = fmaxf(fmaxf(S[0][r], S[1][r]), fmaxf(S[2][r], S[3][r]));
#pragma unroll
      for (int mk = 1; mk <= 8; mk <<= 1) {
#pragma unroll
        for (int r = 0; r < 4; ++r) tm[r] = fmaxf(tm[r], __shfl_xor(tm[r], mk, 64));
      }
      float cr[4];
#pragma unroll
      for (int r = 0; r < 4; ++r) {
        float mn = fmaxf(m[r], tm[r]);
        cr[r] = __expf(m[r] - mn);
        m[r] = mn;
      }
#pragma unroll
      for (int nf = 0; nf < 4; ++nf) {
#pragma unroll
        for (int r = 0; r < 4; ++r) S[nf][r] = __expf(S[nf][r] - m[r]);
      }
#pragma unroll
      for (int r = 0; r < 4; ++r) {
        float ps = S[0][r] + S[1][r] + S[2][r] + S[3][r];
        float p2 = S[0][r] * S[0][r] + S[1][r] * S[1][r] + S[2][r] * S[2][r] + S[3][r] * S[3][r];
        lsum[r] = lsum[r] * cr[r] + ps;
        s2[r] = s2[r] * cr[r] * cr[r] + p2;
      }
      f32x4 cv = {cr[0], cr[1], cr[2], cr[3]};
#pragma unroll
      for (int df = 0; df < 4; ++df) O[df] *= cv;
#pragma unroll
      for (int nf = 0; nf < 4; ++nf) {
#pragma unroll
        for (int r = 0; r < 4; ++r)
          pt[(16 * w + g * 4 + r) * 72 + 16 * nf + li] = f2bf(S[nf][r]);
      }
      // PV: A = P (own-wave strip from LDS), B = V frags straight from L1/L2-hot global q_dmaj
#pragma unroll
      for (int ks = 0; ks < 2; ++ks) {
        u16x8 pa = *(const u16x8*)&pt[(16 * w + li) * 72 + g * 8 + 32 * ks];
#pragma unroll
        for (int df = 0; df < 4; ++df) {
          u16x8 vb = *(const u16x8*)(qdb + (size_t)(16 * df + li) * 1024 + k0 + 32 * ks + 8 * g);
          O[df] = mfma16(pa, vb, O[df]);
        }
      }
    }
    // finalize rows of this j-tile
    f32x4 iv;
    float s2w = 0.f;
#pragma unroll
    for (int r = 0; r < 4; ++r) {
#pragma unroll
      for (int mk = 1; mk <= 8; mk <<= 1) {
        lsum[r] += __shfl_xor(lsum[r], mk, 64);
        s2[r] += __shfl_xor(s2[r], mk, 64);
      }
      float invl = 1.0f / lsum[r];
      iv[r] = invl;
      s2w += s2[r] * invl * invl;
    }
    float vsum = (li == 0) ? s2w : 0.f;
    vsum += __shfl_xor(vsum, 16, 64);
    vsum += __shfl_xor(vsum, 32, 64);
    if (lane == 0) wvar[w] += vsum;
#pragma unroll
    for (int df = 0; df < 4; ++df) {
      O[df] *= iv;
#pragma unroll
      for (int r = 0; r < 4; ++r) {
        float v = O[df][r];
        u16 hv = f2bf(v);
        ol_h[(16 * w + g * 4 + r) * 72 + 16 * df + li] = hv;
        ol_l[(16 * w + g * 4 + r) * 72 + 16 * df + li] = f2bf(v - bf2f(hv));
      }
    }
    __syncthreads();
    {  // fused linear: P_out = W_lin @ (O/l), split-bf16 MFMA; invσ/bias applied in K3
      const int mfr = w & 3;
      u16x8 wa_h[2], wa_l[2];
#pragma unroll
      for (int ks = 0; ks < 2; ++ks) {
        wa_h[ks] = *(const u16x8*)&wl_h[(mfr * 16 + li) * 72 + g * 8 + 32 * ks];
        wa_l[ks] = *(const u16x8*)&wl_l[(mfr * 16 + li) * 72 + g * 8 + 32 * ks];
      }
#pragma unroll
      for (int nfi = 0; nfi < 4; ++nfi) {
        const int nf = (w >> 2) * 4 + nfi;
        f32x4 D = zz;
#pragma unroll
        for (int ks = 0; ks < 2; ++ks) {
          u16x8 oh = *(const u16x8*)&ol_h[(nf * 16 + li) * 72 + g * 8 + 32 * ks];
          u16x8 ol = *(const u16x8*)&ol_l[(nf * 16 + li) * 72 + g * 8 + 32 * ks];
          D = mfma16(wa_h[ks], oh, D);
          D = mfma16(wa_h[ks], ol, D);
          D = mfma16(wa_l[ks], oh, D);
        }
#pragma unroll
        for (int r = 0; r < 4; ++r) {
          int e = mfr * 16 + g * 4 + r;
          int j = j0 + nf * 16 + li;
          pout[((size_t)b * 512 + h * 64 + e) * 1024 + j] = D[r];
        }
      }
    }
  }
  __syncthreads();
  if (t == 0) {
    float s = 0.f;
#pragma unroll
    for (int i = 0; i < 8; ++i) s += wvar[i];
    sump2_g[bh] = s;
  }
  if (t < 64) qsum_g[bh * 64 + t] = qs[t];
}

// ---------------- K3: out = invσ * P_out + (b_lin − invσ·μ·W@qsum)[e] + x  (in-place)
__global__ __launch_bounds__(256) void k_fin(
    float* __restrict__ out, const float* __restrict__ x, const float* __restrict__ Wlin,
    const float* __restrict__ blin, const float* __restrict__ qsum_g,
    const float* __restrict__ sump2_g) {
  const int bh = blockIdx.x, t = threadIdx.x;
  __shared__ float cvec[64], qsl[64];
  if (t < 64) qsl[t] = qsum_g[bh * 64 + t];
  __syncthreads();
  const float MU = 1.0f / 1024.0f;
  float var = sump2_g[bh] * (1.0f / 1048576.0f) - MU * MU;
  float isv = 1.0f / sqrtf(var + EPS);
  if (t < 64) {
    float wq = 0.f;
    for (int d = 0; d < 64; ++d) wq += Wlin[t * 64 + d] * qsl[d];
    cvec[t] = blin[t] - isv * MU * wq;
  }
  __syncthreads();
  const size_t base = (size_t)bh * 65536;
  for (int it = 0; it < 64; ++it) {
    int fl = it * 256 + t;
    size_t off = base + (size_t)fl * 4;
    int e = fl >> 8;  // (fl*4)>>10
    f32x4 po = *(const f32x4*)(out + off);
    f32x4 xv = *(const f32x4*)(x + off);
    float cv = cvec[e];
    f32x4 res;
#pragma unroll
    for (int k = 0; k < 4; ++k) res[k] = isv * po[k] + cv + xv[k];
    *(f32x4*)(out + off) = res;
  }
}

extern "C" void kernel_launch(void* const* d_in, const int* in_sizes, int n_in,
                              void* d_out, int out_size, void* d_ws, size_t ws_size,
                              hipStream_t stream) {
  const float* x = (const float*)d_in[0];
  const float* Ws = (const float*)d_in[1];
  const float* bs = (const float*)d_in[2];
  const float* rh = (const float*)d_in[3];
  const float* rw = (const float*)d_in[4];
  const float* Wl = (const float*)d_in[5];
  const float* bl = (const float*)d_in[6];
  char* wsb = (char*)d_ws;
  u16* qh = (u16*)wsb;                                  // 32 MiB  q hi, n-major [bh][n][d]
  u16* ql = (u16*)(wsb + (size_t)33554432);             // 32 MiB  q lo, n-major
  u16* qd = (u16*)(wsb + (size_t)67108864);             // 32 MiB  q hi, d-major [bh][d][n]
  float* pos_t = (float*)(wsb + (size_t)100663296);     //  2 MiB  pos [h][n][d]
  float* qsg = (float*)(wsb + (size_t)102760448);       // 64 KiB  qsum per (bh,d)
  float* s2g = (float*)(wsb + (size_t)102825984);       //  1 KiB  sum(P~^2) per bh
  float* out = (float*)d_out;

  k_pos<<<2048, 256, 0, stream>>>(rh, rw, pos_t);
  k_conv<<<dim3(8, 16, 32), 256, 0, stream>>>(x, Ws, bs, qh, ql, qd);
  k_attn<<<256, 512, 0, stream>>>(qh, ql, qd, pos_t, Wl, out, qsg, s2g);
  k_fin<<<256, 256, 0, stream>>>(out, x, Wl, bl, qsg, s2g);
}